// Round 28
// baseline (213.348 us; speedup 1.0000x reference)
//
#include <hip/hip_runtime.h>
#include <stdint.h>

typedef unsigned short u16;
typedef __attribute__((ext_vector_type(8))) short short8;
typedef __attribute__((ext_vector_type(4))) float f32x4;
typedef __attribute__((ext_vector_type(8))) u16 u16x8;
typedef __attribute__((ext_vector_type(4))) u16 u16x4;

__device__ __forceinline__ u16 f2bf(float f) {
  union { float f; uint32_t u; } v; v.f = f;
  uint32_t u = v.u;
  uint32_t r = (u + 0x7FFFu + ((u >> 16) & 1u)) >> 16;
  return (u16)r;
}
__device__ __forceinline__ float bf2f(u16 b) {
  union { uint32_t u; float f; } v; v.u = ((uint32_t)b) << 16;
  return v.f;
}

__device__ __forceinline__ void gload16(const u16* g, u16* l) {
  __builtin_amdgcn_global_load_lds(
      (const __attribute__((address_space(1))) void*)g,
      (__attribute__((address_space(3))) void*)l, 16, 0, 0);
}

#define SB0() __builtin_amdgcn_sched_barrier(0)

// ===== champion 256x256 gemm (R15) — QK^T (512 blocks = 2.0 rounds) =====
template<int OMODE>
__global__ __launch_bounds__(512, 2) void gemm_bt(
    const u16* __restrict__ A, long long sAz,
    const u16* __restrict__ Bt, long long sBz,
    u16* __restrict__ C, float* __restrict__ Cf, long long sCz,
    const float* __restrict__ bias, float scale,
    int lda, int ldb, int ldc, int K)
{
  extern __shared__ __align__(16) u16 smem[];
  u16* As = smem;
  u16* Bs = smem + 32768;
  const int tid = threadIdx.x;
  const int w = tid >> 6, l = tid & 63;
  const int wm = w >> 2, wn = w & 3;
  const int z = blockIdx.z;
  A  += sAz * z;
  Bt += sBz * z;
  const long long czoff = sCz * z;
  const long long bm = (long long)blockIdx.x * 256;
  const long long bn = (long long)blockIdx.y * 256;

  const int trow = tid >> 2;
  const int tsl = ((tid & 3) ^ ((tid >> 3) & 3)) * 8;
  const u16* pA0 = A  + (bm + trow) * lda + tsl;
  const u16* pA1 = A  + (bm + 128 + trow) * lda + tsl;
  const u16* pB0 = Bt + (bn + trow) * ldb + tsl;
  const u16* pB1 = Bt + (bn + 128 + trow) * ldb + tsl;
  const int dst8 = tid * 8;

  const int slot = ((l >> 4) ^ (((l & 15) >> 1) & 3)) * 8;
  int al[8], bl[4];
#pragma unroll
  for (int r = 0; r < 8; ++r)
    al[r] = (r * 16 + (l & 15)) * 32 + slot;
#pragma unroll
  for (int c = 0; c < 4; ++c)
    bl[c] = ((wn & 1) * 64 + c * 16 + (l & 15)) * 32 + slot;

  const int nk = K >> 6;

  gload16(pA0,      As + 0 * 4096 + dst8);
  gload16(pA0 + 32, As + 1 * 4096 + dst8);
  gload16(pB0,      Bs + 0 * 4096 + dst8);
  gload16(pB0 + 32, Bs + 1 * 4096 + dst8);
  gload16(pA1,      As + 2 * 4096 + dst8);
  gload16(pA1 + 32, As + 3 * 4096 + dst8);
  gload16(pB1,      Bs + 2 * 4096 + dst8);
  gload16(pB1 + 32, Bs + 3 * 4096 + dst8);
  pA0 += 64; pA1 += 64; pB0 += 64; pB1 += 64;

  f32x4 acc[8][4] = {};

#define MM8(R, CC, AF, BF)                                        \
  __builtin_amdgcn_s_setprio(1);                                  \
  _Pragma("unroll")                                               \
  for (int j = 0; j < 4; ++j)                                     \
    _Pragma("unroll")                                             \
    for (int q = 0; q < 2; ++q)                                   \
      acc[(R) + j][(CC) + q] = __builtin_amdgcn_mfma_f32_16x16x32_bf16( \
          AF[j], BF[q], acc[(R) + j][(CC) + q], 0, 0, 0);         \
  __builtin_amdgcn_s_setprio(0);

  for (int t = 0; t < nk; ++t) {
    asm volatile("s_waitcnt vmcnt(0)" ::: "memory");
    __builtin_amdgcn_s_barrier();
    SB0();
    const int db = (t & 1) * 4;
    const int dn = ((t + 1) & 1) * 4;
    const bool stg = (t + 1 < nk);
    const int paK = db + wm * 2;
    const int pbK = db + (wn >> 1) * 2;
    short8 afA[4], afB[4], bf0[2], bf1[2];
    if (stg) {
      gload16(pA0,      As + (dn + 0) * 4096 + dst8);
      gload16(pA0 + 32, As + (dn + 1) * 4096 + dst8);
      gload16(pB0,      Bs + (dn + 0) * 4096 + dst8);
      gload16(pB0 + 32, Bs + (dn + 1) * 4096 + dst8);
    }
#pragma unroll
    for (int j = 0; j < 4; ++j)
      afA[j] = *(const short8*)(As + paK * 4096 + al[j]);
#pragma unroll
    for (int q = 0; q < 2; ++q)
      bf0[q] = *(const short8*)(Bs + pbK * 4096 + bl[q]);
    SB0();
    MM8(0, 0, afA, bf0);
    SB0();
    if (stg) {
      gload16(pA1,      As + (dn + 2) * 4096 + dst8);
      gload16(pA1 + 32, As + (dn + 3) * 4096 + dst8);
    }
#pragma unroll
    for (int q = 0; q < 2; ++q)
      bf1[q] = *(const short8*)(Bs + pbK * 4096 + bl[2 + q]);
    SB0();
    MM8(0, 2, afA, bf1);
    SB0();
    if (stg) {
      gload16(pB1,      Bs + (dn + 2) * 4096 + dst8);
      gload16(pB1 + 32, Bs + (dn + 3) * 4096 + dst8);
      pA0 += 64; pA1 += 64; pB0 += 64; pB1 += 64;
    }
#pragma unroll
    for (int j = 0; j < 4; ++j)
      afB[j] = *(const short8*)(As + paK * 4096 + al[4 + j]);
    SB0();
    MM8(4, 2, afB, bf1);
    SB0();
    MM8(4, 0, afB, bf0);
    SB0();
#pragma unroll
    for (int j = 0; j < 4; ++j)
      afA[j] = *(const short8*)(As + (paK + 1) * 4096 + al[j]);
#pragma unroll
    for (int q = 0; q < 2; ++q)
      bf0[q] = *(const short8*)(Bs + (pbK + 1) * 4096 + bl[q]);
    SB0();
    MM8(0, 0, afA, bf0);
    SB0();
#pragma unroll
    for (int q = 0; q < 2; ++q)
      bf1[q] = *(const short8*)(Bs + (pbK + 1) * 4096 + bl[2 + q]);
    SB0();
    MM8(0, 2, afA, bf1);
    SB0();
#pragma unroll
    for (int j = 0; j < 4; ++j)
      afB[j] = *(const short8*)(As + (paK + 1) * 4096 + al[4 + j]);
    SB0();
    MM8(4, 2, afB, bf1);
    SB0();
    MM8(4, 0, afB, bf0);
    SB0();
  }
#undef MM8

#pragma unroll
  for (int r = 0; r < 8; ++r) {
#pragma unroll
    for (int c = 0; c < 4; ++c) {
      const long long rr = bm + wm * 128 + r * 16 + (l >> 4) * 4;
      const long long cc = bn + wn * 64 + c * 16 + (l & 15);
      float badd = 0.f;
      if (OMODE == 0) badd = bias[(long long)z * ldc + cc];
#pragma unroll
      for (int i = 0; i < 4; ++i) {
        float v = acc[r][c][i];
        if (OMODE == 0) v += badd;
        if (OMODE == 1) v *= scale;
        C[czoff + (rr + i) * ldc + cc] = f2bf(v);
      }
    }
  }
  (void)Cf;
}

// ===== R28 NEW: 256x384-tile gemm for Q,K (grid 64x2x2 = 256 = 1 round) ==
// LDS: A dbuf 64KB + B dbuf [2db][2kk][384][32] = 96KB -> 160KB total.
// B staged as 6 units of 1 chunk/thread (dest == chunk*8, proven decode
// family). acc[8][6]; per-wave 128x96 output. Same boundary protocol.
__global__ __launch_bounds__(512, 2) void gemm_384(
    const u16* __restrict__ A,
    const u16* __restrict__ Bt, long long sBz,
    u16* __restrict__ C, long long sCz,
    const float* __restrict__ bias,
    int lda, int ldb, int ldc, int K)
{
  extern __shared__ __align__(16) u16 smem[];
  u16* As = smem;                 // 8 planes * 4096 (64KB)
  u16* Bs = smem + 32768;         // [2db][2kk] planes of 12288 (96KB)
  const int tid = threadIdx.x;
  const int w = tid >> 6, l = tid & 63;
  const int wm = w >> 2, wn = w & 3;
  const int z = blockIdx.z;                   // 0=Q, 1=K
  Bt += sBz * z;
  const long long czoff = sCz * z;
  const long long bm = (long long)blockIdx.x * 256;
  const long long bn = (long long)blockIdx.y * 384;

  const int trow = tid >> 2;
  const int tsl = ((tid & 3) ^ ((tid >> 3) & 3)) * 8;
  const u16* pA0 = A + (bm + trow) * lda + tsl;
  const u16* pA1 = A + (bm + 128 + trow) * lda + tsl;
  const int dst8 = tid * 8;

  // B staging: 6 units; chunk = u*512+tid; kk=chunk/1536, rem=chunk%1536,
  // r=rem>>2, s=rem&3; dest = kk*12288 + r*32 + s*8 == chunk*8.
  const u16* srcB[6];
#pragma unroll
  for (int u = 0; u < 6; ++u) {
    const int chunk = u * 512 + tid;
    const int kk = chunk / 1536, rem = chunk - kk * 1536;
    const int r = rem >> 2, s = rem & 3;
    srcB[u] = Bt + (bn + r) * ldb + kk * 32 + ((s ^ ((r >> 1) & 3)) * 8);
  }
  const int dB0 = tid * 8;   // unit u dest = u*4096*... no: chunk*8 = u*4096+tid*8
  (void)dB0;

  const int slot = ((l >> 4) ^ (((l & 15) >> 1) & 3)) * 8;
  int al[8], bl[6];
#pragma unroll
  for (int r = 0; r < 8; ++r)
    al[r] = (r * 16 + (l & 15)) * 32 + slot;
#pragma unroll
  for (int c = 0; c < 6; ++c)
    bl[c] = (wn * 96 + c * 16 + (l & 15)) * 32 + slot;

  const int nk = K >> 6;

  // prologue: tile 0 into db=0 (A 4 + B 6 loads)
  gload16(pA0,      As + 0 * 4096 + dst8);
  gload16(pA0 + 32, As + 1 * 4096 + dst8);
  gload16(pA1,      As + 2 * 4096 + dst8);
  gload16(pA1 + 32, As + 3 * 4096 + dst8);
#pragma unroll
  for (int u = 0; u < 6; ++u)
    gload16(srcB[u], Bs + u * 4096 + tid * 8);
  pA0 += 64; pA1 += 64;
#pragma unroll
  for (int u = 0; u < 6; ++u) srcB[u] += 64;

  f32x4 acc[8][6] = {};

#define MM24(R, AF, BF)                                                  \
  __builtin_amdgcn_s_setprio(1);                                         \
  _Pragma("unroll")                                                      \
  for (int j = 0; j < 4; ++j)                                            \
    _Pragma("unroll")                                                    \
    for (int q = 0; q < 6; ++q)                                          \
      acc[(R) + j][q] = __builtin_amdgcn_mfma_f32_16x16x32_bf16(         \
          AF[j], BF[q], acc[(R) + j][q], 0, 0, 0);                       \
  __builtin_amdgcn_s_setprio(0);

  for (int t = 0; t < nk; ++t) {
    asm volatile("s_waitcnt vmcnt(0)" ::: "memory");
    __builtin_amdgcn_s_barrier();
    SB0();
    const int dbA = (t & 1) * 4;
    const int dnA = ((t + 1) & 1) * 4;
    const int dbB = (t & 1) * 24576;
    const int dnB = ((t + 1) & 1) * 24576;
    const bool stg = (t + 1 < nk);
    const int paK = dbA + wm * 2;
    short8 afA[4], afB[4], bf0[6], bf1[6];
    // stage A-half0 + B units 0-2
    if (stg) {
      gload16(pA0,      As + (dnA + 0) * 4096 + dst8);
      gload16(pA0 + 32, As + (dnA + 1) * 4096 + dst8);
      gload16(srcB[0], Bs + dnB + 0 * 4096 + tid * 8);
      gload16(srcB[1], Bs + dnB + 1 * 4096 + tid * 8);
      gload16(srcB[2], Bs + dnB + 2 * 4096 + tid * 8);
    }
    // ph0: af r0-3 kk0, bf kk0 (6); MFMA 24
#pragma unroll
    for (int j = 0; j < 4; ++j)
      afA[j] = *(const short8*)(As + paK * 4096 + al[j]);
#pragma unroll
    for (int q = 0; q < 6; ++q)
      bf0[q] = *(const short8*)(Bs + dbB + bl[q]);
    SB0();
    MM24(0, afA, bf0);
    SB0();
    // ph1: stage A-half1 + B units 3-5; af r4-7 kk0; MFMA 24
    if (stg) {
      gload16(pA1,      As + (dnA + 2) * 4096 + dst8);
      gload16(pA1 + 32, As + (dnA + 3) * 4096 + dst8);
      gload16(srcB[3], Bs + dnB + 3 * 4096 + tid * 8);
      gload16(srcB[4], Bs + dnB + 4 * 4096 + tid * 8);
      gload16(srcB[5], Bs + dnB + 5 * 4096 + tid * 8);
      pA0 += 64; pA1 += 64;
#pragma unroll
      for (int u = 0; u < 6; ++u) srcB[u] += 64;
    }
#pragma unroll
    for (int j = 0; j < 4; ++j)
      afB[j] = *(const short8*)(As + paK * 4096 + al[4 + j]);
    SB0();
    MM24(4, afB, bf0);
    SB0();
    // ph2: af r0-3 kk1, bf kk1; MFMA 24
#pragma unroll
    for (int j = 0; j < 4; ++j)
      afA[j] = *(const short8*)(As + (paK + 1) * 4096 + al[j]);
#pragma unroll
    for (int q = 0; q < 6; ++q)
      bf1[q] = *(const short8*)(Bs + dbB + 12288 + bl[q]);
    SB0();
    MM24(0, afA, bf1);
    SB0();
    // ph3: af r4-7 kk1; MFMA 24
#pragma unroll
    for (int j = 0; j < 4; ++j)
      afB[j] = *(const short8*)(As + (paK + 1) * 4096 + al[4 + j]);
    SB0();
    MM24(4, afB, bf1);
    SB0();
  }
#undef MM24

  // epilogue: +bias, bf16 store (oracle-verified C/D map)
#pragma unroll
  for (int r = 0; r < 8; ++r) {
#pragma unroll
    for (int c = 0; c < 6; ++c) {
      const long long rr = bm + wm * 128 + r * 16 + (l >> 4) * 4;
      const long long cc = bn + wn * 96 + c * 16 + (l & 15);
      const float badd = bias[(long long)z * ldc + cc];
#pragma unroll
      for (int i = 0; i < 4; ++i)
        C[czoff + (rr + i) * ldc + cc] = f2bf(acc[r][c][i] + badd);
    }
  }
}

// ===== 256x192-tile gemm (R22-R27 proven) ================================
// OMODE 0 = +bias, bf16 store; z==2 writes V TRANSPOSED to vt via LDS
//           bounce (coalesced). zoff shifts blockIdx.z (V launch: zoff=2).
// OMODE 2 = plain, f32 store (PV, 256 blocks = 1.0 round).
template<int OMODE>
__global__ __launch_bounds__(512, 2) void gemm_192(
    const u16* __restrict__ A, long long sAz,
    const u16* __restrict__ Bt, long long sBz,
    u16* __restrict__ C, float* __restrict__ Cf, long long sCz,
    const float* __restrict__ bias, u16* __restrict__ Vt, int zoff,
    int lda, int ldb, int ldc, int K)
{
  extern __shared__ __align__(16) u16 smem[];
  u16* As = smem;                 // 8 planes * 4096
  u16* Bs = smem + 32768;         // 2 db * 12288
  const int tid = threadIdx.x;
  const int w = tid >> 6, l = tid & 63;
  const int wm = w >> 2, wn = w & 3;
  const int z = blockIdx.z + zoff;
  A  += sAz * z;
  Bt += sBz * z;
  const long long czoff = sCz * z;
  const long long bm = (long long)blockIdx.x * 256;
  const long long bn = (long long)blockIdx.y * 192;

  const int trow = tid >> 2;
  const int tsl = ((tid & 3) ^ ((tid >> 3) & 3)) * 8;
  const u16* pA0 = A + (bm + trow) * lda + tsl;
  const u16* pA1 = A + (bm + 128 + trow) * lda + tsl;
  const int dst8 = tid * 8;

  const u16* srcB[3];
  int dstB[3];
#pragma unroll
  for (int u = 0; u < 3; ++u) {
    const int chunk = u * 512 + tid;
    const int kk = chunk / 768, rem = chunk - kk * 768;
    const int r = rem >> 2, s = rem & 3;
    srcB[u] = Bt + (bn + r) * ldb + kk * 32 + ((s ^ ((r >> 1) & 3)) * 8);
    dstB[u] = kk * 6144 + r * 32 + s * 8;   // == chunk*8
  }

  const int slot = ((l >> 4) ^ (((l & 15) >> 1) & 3)) * 8;
  int al[8], bl[3];
#pragma unroll
  for (int r = 0; r < 8; ++r)
    al[r] = (r * 16 + (l & 15)) * 32 + slot;
#pragma unroll
  for (int c = 0; c < 3; ++c)
    bl[c] = (wn * 48 + c * 16 + (l & 15)) * 32 + slot;

  const int nk = K >> 6;

  gload16(pA0,      As + 0 * 4096 + dst8);
  gload16(pA0 + 32, As + 1 * 4096 + dst8);
  gload16(pA1,      As + 2 * 4096 + dst8);
  gload16(pA1 + 32, As + 3 * 4096 + dst8);
  gload16(srcB[0], Bs + dstB[0]);
  gload16(srcB[1], Bs + dstB[1]);
  gload16(srcB[2], Bs + dstB[2]);
  pA0 += 64; pA1 += 64;
  srcB[0] += 64; srcB[1] += 64; srcB[2] += 64;

  f32x4 acc[8][3] = {};

#define MM12(R, AF, BF)                                                  \
  __builtin_amdgcn_s_setprio(1);                                         \
  _Pragma("unroll")                                                      \
  for (int j = 0; j < 4; ++j)                                            \
    _Pragma("unroll")                                                    \
    for (int q = 0; q < 3; ++q)                                          \
      acc[(R) + j][q] = __builtin_amdgcn_mfma_f32_16x16x32_bf16(         \
          AF[j], BF[q], acc[(R) + j][q], 0, 0, 0);                       \
  __builtin_amdgcn_s_setprio(0);

  for (int t = 0; t < nk; ++t) {
    asm volatile("s_waitcnt vmcnt(0)" ::: "memory");
    __builtin_amdgcn_s_barrier();
    SB0();
    const int dbA = (t & 1) * 4;
    const int dnA = ((t + 1) & 1) * 4;
    const int dbB = (t & 1) * 12288;
    const int dnB = ((t + 1) & 1) * 12288;
    const bool stg = (t + 1 < nk);
    const int paK = dbA + wm * 2;
    short8 afA[4], afB[4], bf0[3], bf1[3];
    if (stg) {
      gload16(pA0,      As + (dnA + 0) * 4096 + dst8);
      gload16(pA0 + 32, As + (dnA + 1) * 4096 + dst8);
      gload16(srcB[0], Bs + dnB + dstB[0]);
    }
#pragma unroll
    for (int j = 0; j < 4; ++j)
      afA[j] = *(const short8*)(As + paK * 4096 + al[j]);
#pragma unroll
    for (int q = 0; q < 3; ++q)
      bf0[q] = *(const short8*)(Bs + dbB + bl[q]);
    SB0();
    MM12(0, afA, bf0);
    SB0();
    if (stg) {
      gload16(pA1,      As + (dnA + 2) * 4096 + dst8);
      gload16(pA1 + 32, As + (dnA + 3) * 4096 + dst8);
      gload16(srcB[1], Bs + dnB + dstB[1]);
    }
#pragma unroll
    for (int j = 0; j < 4; ++j)
      afB[j] = *(const short8*)(As + paK * 4096 + al[4 + j]);
    SB0();
    MM12(4, afB, bf0);
    SB0();
    if (stg) {
      gload16(srcB[2], Bs + dnB + dstB[2]);
      pA0 += 64; pA1 += 64;
      srcB[0] += 64; srcB[1] += 64; srcB[2] += 64;
    }
#pragma unroll
    for (int j = 0; j < 4; ++j)
      afA[j] = *(const short8*)(As + (paK + 1) * 4096 + al[j]);
#pragma unroll
    for (int q = 0; q < 3; ++q)
      bf1[q] = *(const short8*)(Bs + dbB + 6144 + bl[q]);
    SB0();
    MM12(0, afA, bf1);
    SB0();
#pragma unroll
    for (int j = 0; j < 4; ++j)
      afB[j] = *(const short8*)(As + (paK + 1) * 4096 + al[4 + j]);
    SB0();
    MM12(4, afB, bf1);
    SB0();
  }
#undef MM12

  // epilogue (oracle-verified C/D map)
  const bool vtr = (OMODE == 0) && (z == 2);   // block-uniform
  if (vtr) {
    u16* T = smem;  // [192][264] padded transpose buffer (101376 B)
    __syncthreads();
#pragma unroll
    for (int r = 0; r < 8; ++r) {
#pragma unroll
      for (int c = 0; c < 3; ++c) {
        const int lrow = wn * 48 + c * 16 + (l & 15);
        const int lcol = wm * 128 + r * 16 + (l >> 4) * 4;
        const float badd = bias[(long long)z * ldc + (bn + lrow)];
        u16x4 o;
#pragma unroll
        for (int i = 0; i < 4; ++i) o[i] = f2bf(acc[r][c][i] + badd);
        *(u16x4*)(T + lrow * 264 + lcol) = o;
      }
    }
    __syncthreads();
    const long long b = bm >> 11;
    const int m0 = (int)(bm & 2047);
    for (int ch = tid; ch < 192 * 32; ch += 512) {
      const int row = ch >> 5, c8 = (ch & 31) * 8;
      u16x8 v = *(const u16x8*)(T + row * 264 + c8);
      *(u16x8*)(Vt + (b * 768 + bn + row) * 2048 + m0 + c8) = v;
    }
  } else {
#pragma unroll
    for (int r = 0; r < 8; ++r) {
#pragma unroll
      for (int c = 0; c < 3; ++c) {
        const long long rr = bm + wm * 128 + r * 16 + (l >> 4) * 4;
        const long long cc = bn + wn * 48 + c * 16 + (l & 15);
        float badd = 0.f;
        if (OMODE == 0) badd = bias[(long long)z * ldc + cc];
#pragma unroll
        for (int i = 0; i < 4; ++i) {
          float v = acc[r][c][i];
          if (OMODE == 0)
            C[czoff + (rr + i) * ldc + cc] = f2bf(v + badd);
          else
            Cf[czoff + (rr + i) * ldc + cc] = v;
        }
      }
    }
  }
}

// f32 -> bf16, 4 elems/thread, grid-stride
__global__ __launch_bounds__(256) void cvt_f32_bf16(
    const float* __restrict__ src, u16* __restrict__ dst, int n4)
{
  int i = blockIdx.x * 256 + threadIdx.x;
  const int stride = gridDim.x * 256;
  for (; i < n4; i += stride) {
    f32x4 v = *(const f32x4*)(src + (long long)i * 4);
    u16x4 o;
    o[0] = f2bf(v[0]); o[1] = f2bf(v[1]);
    o[2] = f2bf(v[2]); o[3] = f2bf(v[3]);
    *(u16x4*)(dst + (long long)i * 4) = o;
  }
}

// W f32 [d][e] -> wt bf16 [z][e][d]
__global__ void prep_w(const float* __restrict__ Wq, const float* __restrict__ Wk,
                       const float* __restrict__ Wv, u16* __restrict__ wt)
{
  __shared__ float tile[32][33];
  const int zz = blockIdx.z;
  const float* W = zz == 0 ? Wq : (zz == 1 ? Wk : Wv);
  const int e0 = blockIdx.x * 32, d0 = blockIdx.y * 32;
  const int tx = threadIdx.x, ty = threadIdx.y;
#pragma unroll
  for (int i = 0; i < 4; ++i)
    tile[ty + i * 8][tx] = W[(long long)(d0 + ty + i * 8) * 768 + e0 + tx];
  __syncthreads();
  u16* dst = wt + (long long)zz * 768 * 768;
#pragma unroll
  for (int i = 0; i < 4; ++i)
    dst[(long long)(e0 + ty + i * 8) * 768 + d0 + tx] = f2bf(tile[tx][ty + i * 8]);
}

// biases f32: pack into contiguous [3][768]
__global__ void prep_b(const float* bq, const float* bk, const float* bv, float* dst)
{
  const int zz = blockIdx.x;
  const float* s = zz == 0 ? bq : (zz == 1 ? bk : bv);
  for (int i = threadIdx.x; i < 768; i += 256) dst[zz * 768 + i] = s[i];
}

// in-place row softmax on bf16 [rows][2048]; one block (256 thr) per row
__global__ __launch_bounds__(256) void softmax_rows(u16* __restrict__ p)
{
  const long long row = blockIdx.x;
  u16* r = p + row * 2048;
  const int t = threadIdx.x;
  const int l = t & 63, w = t >> 6;
  u16x8 vv = *(const u16x8*)(r + t * 8);
  float x[8];
#pragma unroll
  for (int i = 0; i < 8; ++i) x[i] = bf2f(vv[i]);
  float m = x[0];
#pragma unroll
  for (int i = 1; i < 8; ++i) m = fmaxf(m, x[i]);
#pragma unroll
  for (int off = 32; off >= 1; off >>= 1) m = fmaxf(m, __shfl_xor(m, off, 64));
  __shared__ float redm[4], reds[4];
  if (l == 0) redm[w] = m;
  __syncthreads();
  m = fmaxf(fmaxf(redm[0], redm[1]), fmaxf(redm[2], redm[3]));
  float s = 0.f;
#pragma unroll
  for (int i = 0; i < 8; ++i) { x[i] = expf(x[i] - m); s += x[i]; }
#pragma unroll
  for (int off = 32; off >= 1; off >>= 1) s += __shfl_xor(s, off, 64);
  if (l == 0) reds[w] = s;
  __syncthreads();
  s = reds[0] + reds[1] + reds[2] + reds[3];
  const float inv = 1.0f / s;
  u16x8 ov;
#pragma unroll
  for (int i = 0; i < 8; ++i) ov[i] = f2bf(x[i] * inv);
  *(u16x8*)(r + t * 8) = ov;
}

extern "C" void kernel_launch(void* const* d_in, const int* in_sizes, int n_in,
                              void* d_out, int out_size, void* d_ws, size_t ws_size,
                              hipStream_t stream)
{
  (void)in_sizes; (void)n_in; (void)out_size;
  const float* x  = (const float*)d_in[0];
  const float* Wq = (const float*)d_in[1];
  const float* bq = (const float*)d_in[2];
  const float* Wk = (const float*)d_in[3];
  const float* bk = (const float*)d_in[4];
  const float* Wv = (const float*)d_in[5];
  const float* bv = (const float*)d_in[6];
  float* out = (float*)d_out;   // reference output dtype = float32

  // ws layout (bytes): wt @0; qb @3538944; kb follows; vt @79036416;
  // p @104202240 (xb aliased); wsb @171311104. total 171,320,320.
  const size_t NEEDED = 171320320;
  if (ws_size < NEEDED) return;

  char* ws = (char*)d_ws;
  u16* wt  = (u16*)ws;
  u16* qb  = (u16*)(ws + 3538944);
  u16* vt  = (u16*)(ws + 79036416);
  u16* p   = (u16*)(ws + 104202240);
  u16* xb  = p;  // alias: x(bf16) dead before QK^T writes p
  float* wsb = (float*)(ws + 171311104);
  u16* kb = qb + (long long)16384 * 768;

  // allow large dynamic LDS (idempotent; capture-safe)
  hipFuncSetAttribute((const void*)&gemm_bt<1>,
                      hipFuncAttributeMaxDynamicSharedMemorySize, 131072);
  hipFuncSetAttribute((const void*)&gemm_384,
                      hipFuncAttributeMaxDynamicSharedMemorySize, 163840);
  hipFuncSetAttribute((const void*)&gemm_192<0>,
                      hipFuncAttributeMaxDynamicSharedMemorySize, 131072);
  hipFuncSetAttribute((const void*)&gemm_192<2>,
                      hipFuncAttributeMaxDynamicSharedMemorySize, 131072);

  cvt_f32_bf16<<<4096, 256, 0, stream>>>(x, xb, 3145728);
  prep_w<<<dim3(24, 24, 3), dim3(32, 8), 0, stream>>>(Wq, Wk, Wv, wt);
  prep_b<<<3, 256, 0, stream>>>(bq, bk, bv, wsb);

  // q,k = x @ W + b — 256x384 tiles, grid 64x2x2 = 256 blocks = 1.0 round
  gemm_384<<<dim3(64, 2, 2), 512, 163840, stream>>>(
      xb, wt, 768LL * 768, qb, 16384LL * 768, wsb,
      768, 768, 768, 768);

  // v = x @ Wv + bv — 256x192 tiles, grid 64x4x1 (zoff=2) = 256 = 1.0 round;
  // writes TRANSPOSED to vt via LDS bounce.
  gemm_192<0><<<dim3(64, 4, 1), 512, 114688, stream>>>(
      xb, 0LL, wt, 768LL * 768, qb, nullptr, 16384LL * 768, wsb, vt, 2,
      768, 768, 768, 768);

  // scores = (q @ k^T) / sqrt(768)  per batch — 512 blocks = 2.0 rounds
  gemm_bt<1><<<dim3(8, 8, 8), 512, 131072, stream>>>(
      qb, 2048LL * 768, kb, 2048LL * 768, p, nullptr, 2048LL * 2048, nullptr,
      0.03608439182435161f, 768, 768, 2048, 768);

  softmax_rows<<<16384, 256, 0, stream>>>(p);

  // out = p @ v  per batch -> f32 — 256x192 tiles, 256 blocks = 1.0 round
  gemm_192<2><<<dim3(8, 4, 8), 512, 114688, stream>>>(
      p, 2048LL * 2048, vt, 768LL * 2048, nullptr, out, 2048LL * 768, nullptr,
      nullptr, 0, 2048, 2048, 768, 2048);
}

// Round 31
// 211.459 us; speedup vs baseline: 1.0089x; 1.0089x over previous
//
#include <hip/hip_runtime.h>
#include <stdint.h>

typedef unsigned short u16;
typedef __attribute__((ext_vector_type(8))) short short8;
typedef __attribute__((ext_vector_type(4))) float f32x4;
typedef __attribute__((ext_vector_type(8))) u16 u16x8;
typedef __attribute__((ext_vector_type(4))) u16 u16x4;

__device__ __forceinline__ u16 f2bf(float f) {
  union { float f; uint32_t u; } v; v.f = f;
  uint32_t u = v.u;
  uint32_t r = (u + 0x7FFFu + ((u >> 16) & 1u)) >> 16;
  return (u16)r;
}
__device__ __forceinline__ float bf2f(u16 b) {
  union { uint32_t u; float f; } v; v.u = ((uint32_t)b) << 16;
  return v.f;
}

__device__ __forceinline__ void gload16(const u16* g, u16* l) {
  __builtin_amdgcn_global_load_lds(
      (const __attribute__((address_space(1))) void*)g,
      (__attribute__((address_space(3))) void*)l, 16, 0, 0);
}

#define SB0() __builtin_amdgcn_sched_barrier(0)

// ===== champion 256x256 gemm (R15) — QK^T (512 blocks = 2.0 rounds) =====
template<int OMODE>
__global__ __launch_bounds__(512, 2) void gemm_bt(
    const u16* __restrict__ A, long long sAz,
    const u16* __restrict__ Bt, long long sBz,
    u16* __restrict__ C, float* __restrict__ Cf, long long sCz,
    const float* __restrict__ bias, float scale,
    int lda, int ldb, int ldc, int K)
{
  extern __shared__ __align__(16) u16 smem[];
  u16* As = smem;
  u16* Bs = smem + 32768;
  const int tid = threadIdx.x;
  const int w = tid >> 6, l = tid & 63;
  const int wm = w >> 2, wn = w & 3;
  const int z = blockIdx.z;
  A  += sAz * z;
  Bt += sBz * z;
  const long long czoff = sCz * z;
  const long long bm = (long long)blockIdx.x * 256;
  const long long bn = (long long)blockIdx.y * 256;

  const int trow = tid >> 2;
  const int tsl = ((tid & 3) ^ ((tid >> 3) & 3)) * 8;
  const u16* pA0 = A  + (bm + trow) * lda + tsl;
  const u16* pA1 = A  + (bm + 128 + trow) * lda + tsl;
  const u16* pB0 = Bt + (bn + trow) * ldb + tsl;
  const u16* pB1 = Bt + (bn + 128 + trow) * ldb + tsl;
  const int dst8 = tid * 8;

  const int slot = ((l >> 4) ^ (((l & 15) >> 1) & 3)) * 8;
  int al[8], bl[4];
#pragma unroll
  for (int r = 0; r < 8; ++r)
    al[r] = (r * 16 + (l & 15)) * 32 + slot;
#pragma unroll
  for (int c = 0; c < 4; ++c)
    bl[c] = ((wn & 1) * 64 + c * 16 + (l & 15)) * 32 + slot;

  const int nk = K >> 6;

  gload16(pA0,      As + 0 * 4096 + dst8);
  gload16(pA0 + 32, As + 1 * 4096 + dst8);
  gload16(pB0,      Bs + 0 * 4096 + dst8);
  gload16(pB0 + 32, Bs + 1 * 4096 + dst8);
  gload16(pA1,      As + 2 * 4096 + dst8);
  gload16(pA1 + 32, As + 3 * 4096 + dst8);
  gload16(pB1,      Bs + 2 * 4096 + dst8);
  gload16(pB1 + 32, Bs + 3 * 4096 + dst8);
  pA0 += 64; pA1 += 64; pB0 += 64; pB1 += 64;

  f32x4 acc[8][4] = {};

#define MM8(R, CC, AF, BF)                                        \
  __builtin_amdgcn_s_setprio(1);                                  \
  _Pragma("unroll")                                               \
  for (int j = 0; j < 4; ++j)                                     \
    _Pragma("unroll")                                             \
    for (int q = 0; q < 2; ++q)                                   \
      acc[(R) + j][(CC) + q] = __builtin_amdgcn_mfma_f32_16x16x32_bf16( \
          AF[j], BF[q], acc[(R) + j][(CC) + q], 0, 0, 0);         \
  __builtin_amdgcn_s_setprio(0);

  for (int t = 0; t < nk; ++t) {
    asm volatile("s_waitcnt vmcnt(0)" ::: "memory");
    __builtin_amdgcn_s_barrier();
    SB0();
    const int db = (t & 1) * 4;
    const int dn = ((t + 1) & 1) * 4;
    const bool stg = (t + 1 < nk);
    const int paK = db + wm * 2;
    const int pbK = db + (wn >> 1) * 2;
    short8 afA[4], afB[4], bf0[2], bf1[2];
    if (stg) {
      gload16(pA0,      As + (dn + 0) * 4096 + dst8);
      gload16(pA0 + 32, As + (dn + 1) * 4096 + dst8);
      gload16(pB0,      Bs + (dn + 0) * 4096 + dst8);
      gload16(pB0 + 32, Bs + (dn + 1) * 4096 + dst8);
    }
#pragma unroll
    for (int j = 0; j < 4; ++j)
      afA[j] = *(const short8*)(As + paK * 4096 + al[j]);
#pragma unroll
    for (int q = 0; q < 2; ++q)
      bf0[q] = *(const short8*)(Bs + pbK * 4096 + bl[q]);
    SB0();
    MM8(0, 0, afA, bf0);
    SB0();
    if (stg) {
      gload16(pA1,      As + (dn + 2) * 4096 + dst8);
      gload16(pA1 + 32, As + (dn + 3) * 4096 + dst8);
    }
#pragma unroll
    for (int q = 0; q < 2; ++q)
      bf1[q] = *(const short8*)(Bs + pbK * 4096 + bl[2 + q]);
    SB0();
    MM8(0, 2, afA, bf1);
    SB0();
    if (stg) {
      gload16(pB1,      Bs + (dn + 2) * 4096 + dst8);
      gload16(pB1 + 32, Bs + (dn + 3) * 4096 + dst8);
      pA0 += 64; pA1 += 64; pB0 += 64; pB1 += 64;
    }
#pragma unroll
    for (int j = 0; j < 4; ++j)
      afB[j] = *(const short8*)(As + paK * 4096 + al[4 + j]);
    SB0();
    MM8(4, 2, afB, bf1);
    SB0();
    MM8(4, 0, afB, bf0);
    SB0();
#pragma unroll
    for (int j = 0; j < 4; ++j)
      afA[j] = *(const short8*)(As + (paK + 1) * 4096 + al[j]);
#pragma unroll
    for (int q = 0; q < 2; ++q)
      bf0[q] = *(const short8*)(Bs + (pbK + 1) * 4096 + bl[q]);
    SB0();
    MM8(0, 0, afA, bf0);
    SB0();
#pragma unroll
    for (int q = 0; q < 2; ++q)
      bf1[q] = *(const short8*)(Bs + (pbK + 1) * 4096 + bl[2 + q]);
    SB0();
    MM8(0, 2, afA, bf1);
    SB0();
#pragma unroll
    for (int j = 0; j < 4; ++j)
      afB[j] = *(const short8*)(As + (paK + 1) * 4096 + al[4 + j]);
    SB0();
    MM8(4, 2, afB, bf1);
    SB0();
    MM8(4, 0, afB, bf0);
    SB0();
  }
#undef MM8

#pragma unroll
  for (int r = 0; r < 8; ++r) {
#pragma unroll
    for (int c = 0; c < 4; ++c) {
      const long long rr = bm + wm * 128 + r * 16 + (l >> 4) * 4;
      const long long cc = bn + wn * 64 + c * 16 + (l & 15);
      float badd = 0.f;
      if (OMODE == 0) badd = bias[(long long)z * ldc + cc];
#pragma unroll
      for (int i = 0; i < 4; ++i) {
        float v = acc[r][c][i];
        if (OMODE == 0) v += badd;
        if (OMODE == 1) v *= scale;
        C[czoff + (rr + i) * ldc + cc] = f2bf(v);
      }
    }
  }
  (void)Cf;
}

// ===== 256x192-tile gemm (R22-R27 proven) ================================
// 13 params: A,sAz,Bt,sBz,C,Cf,sCz,bias,Vt,lda,ldb,ldc,K.
// OMODE 0 = +bias, bf16 store (QKV, grid 64x4x3 = 768 blocks = 3.0 rounds;
//           z==2 writes V TRANSPOSED to vt via LDS bounce);
// OMODE 2 = plain, f32 store (PV, grid 8x4x8 = 256 blocks = 1.0 round).
template<int OMODE>
__global__ __launch_bounds__(512, 2) void gemm_192(
    const u16* __restrict__ A, long long sAz,
    const u16* __restrict__ Bt, long long sBz,
    u16* __restrict__ C, float* __restrict__ Cf, long long sCz,
    const float* __restrict__ bias, u16* __restrict__ Vt,
    int lda, int ldb, int ldc, int K)
{
  extern __shared__ __align__(16) u16 smem[];
  u16* As = smem;                 // 8 planes * 4096
  u16* Bs = smem + 32768;         // 2 db * 12288
  const int tid = threadIdx.x;
  const int w = tid >> 6, l = tid & 63;
  const int wm = w >> 2, wn = w & 3;
  const int z = blockIdx.z;
  A  += sAz * z;
  Bt += sBz * z;
  const long long czoff = sCz * z;
  const long long bm = (long long)blockIdx.x * 256;
  const long long bn = (long long)blockIdx.y * 192;

  const int trow = tid >> 2;
  const int tsl = ((tid & 3) ^ ((tid >> 3) & 3)) * 8;
  const u16* pA0 = A + (bm + trow) * lda + tsl;
  const u16* pA1 = A + (bm + 128 + trow) * lda + tsl;
  const int dst8 = tid * 8;

  const u16* srcB[3];
  int dstB[3];
#pragma unroll
  for (int u = 0; u < 3; ++u) {
    const int chunk = u * 512 + tid;
    const int kk = chunk / 768, rem = chunk - kk * 768;
    const int r = rem >> 2, s = rem & 3;
    srcB[u] = Bt + (bn + r) * ldb + kk * 32 + ((s ^ ((r >> 1) & 3)) * 8);
    dstB[u] = kk * 6144 + r * 32 + s * 8;   // == chunk*8
  }

  const int slot = ((l >> 4) ^ (((l & 15) >> 1) & 3)) * 8;
  int al[8], bl[3];
#pragma unroll
  for (int r = 0; r < 8; ++r)
    al[r] = (r * 16 + (l & 15)) * 32 + slot;
#pragma unroll
  for (int c = 0; c < 3; ++c)
    bl[c] = (wn * 48 + c * 16 + (l & 15)) * 32 + slot;

  const int nk = K >> 6;

  gload16(pA0,      As + 0 * 4096 + dst8);
  gload16(pA0 + 32, As + 1 * 4096 + dst8);
  gload16(pA1,      As + 2 * 4096 + dst8);
  gload16(pA1 + 32, As + 3 * 4096 + dst8);
  gload16(srcB[0], Bs + dstB[0]);
  gload16(srcB[1], Bs + dstB[1]);
  gload16(srcB[2], Bs + dstB[2]);
  pA0 += 64; pA1 += 64;
  srcB[0] += 64; srcB[1] += 64; srcB[2] += 64;

  f32x4 acc[8][3] = {};

#define MM12(R, AF, BF)                                                  \
  __builtin_amdgcn_s_setprio(1);                                         \
  _Pragma("unroll")                                                      \
  for (int j = 0; j < 4; ++j)                                            \
    _Pragma("unroll")                                                    \
    for (int q = 0; q < 3; ++q)                                          \
      acc[(R) + j][q] = __builtin_amdgcn_mfma_f32_16x16x32_bf16(         \
          AF[j], BF[q], acc[(R) + j][q], 0, 0, 0);                       \
  __builtin_amdgcn_s_setprio(0);

  for (int t = 0; t < nk; ++t) {
    asm volatile("s_waitcnt vmcnt(0)" ::: "memory");
    __builtin_amdgcn_s_barrier();
    SB0();
    const int dbA = (t & 1) * 4;
    const int dnA = ((t + 1) & 1) * 4;
    const int dbB = (t & 1) * 12288;
    const int dnB = ((t + 1) & 1) * 12288;
    const bool stg = (t + 1 < nk);
    const int paK = dbA + wm * 2;
    short8 afA[4], afB[4], bf0[3], bf1[3];
    if (stg) {
      gload16(pA0,      As + (dnA + 0) * 4096 + dst8);
      gload16(pA0 + 32, As + (dnA + 1) * 4096 + dst8);
      gload16(srcB[0], Bs + dnB + dstB[0]);
    }
#pragma unroll
    for (int j = 0; j < 4; ++j)
      afA[j] = *(const short8*)(As + paK * 4096 + al[j]);
#pragma unroll
    for (int q = 0; q < 3; ++q)
      bf0[q] = *(const short8*)(Bs + dbB + bl[q]);
    SB0();
    MM12(0, afA, bf0);
    SB0();
    if (stg) {
      gload16(pA1,      As + (dnA + 2) * 4096 + dst8);
      gload16(pA1 + 32, As + (dnA + 3) * 4096 + dst8);
      gload16(srcB[1], Bs + dnB + dstB[1]);
    }
#pragma unroll
    for (int j = 0; j < 4; ++j)
      afB[j] = *(const short8*)(As + paK * 4096 + al[4 + j]);
    SB0();
    MM12(4, afB, bf0);
    SB0();
    if (stg) {
      gload16(srcB[2], Bs + dnB + dstB[2]);
      pA0 += 64; pA1 += 64;
      srcB[0] += 64; srcB[1] += 64; srcB[2] += 64;
    }
#pragma unroll
    for (int j = 0; j < 4; ++j)
      afA[j] = *(const short8*)(As + (paK + 1) * 4096 + al[j]);
#pragma unroll
    for (int q = 0; q < 3; ++q)
      bf1[q] = *(const short8*)(Bs + dbB + 6144 + bl[q]);
    SB0();
    MM12(0, afA, bf1);
    SB0();
#pragma unroll
    for (int j = 0; j < 4; ++j)
      afB[j] = *(const short8*)(As + (paK + 1) * 4096 + al[4 + j]);
    SB0();
    MM12(4, afB, bf1);
    SB0();
  }
#undef MM12

  // epilogue (oracle-verified C/D map)
  const bool vtr = (OMODE == 0) && (z == 2);   // block-uniform
  if (vtr) {
    u16* T = smem;  // [192][264] padded transpose buffer (101376 B)
    __syncthreads();
#pragma unroll
    for (int r = 0; r < 8; ++r) {
#pragma unroll
      for (int c = 0; c < 3; ++c) {
        const int lrow = wn * 48 + c * 16 + (l & 15);
        const int lcol = wm * 128 + r * 16 + (l >> 4) * 4;
        const float badd = bias[(long long)z * ldc + (bn + lrow)];
        u16x4 o;
#pragma unroll
        for (int i = 0; i < 4; ++i) o[i] = f2bf(acc[r][c][i] + badd);
        *(u16x4*)(T + lrow * 264 + lcol) = o;
      }
    }
    __syncthreads();
    const long long b = bm >> 11;
    const int m0 = (int)(bm & 2047);
    for (int ch = tid; ch < 192 * 32; ch += 512) {
      const int row = ch >> 5, c8 = (ch & 31) * 8;
      u16x8 v = *(const u16x8*)(T + row * 264 + c8);
      *(u16x8*)(Vt + (b * 768 + bn + row) * 2048 + m0 + c8) = v;
    }
  } else {
#pragma unroll
    for (int r = 0; r < 8; ++r) {
#pragma unroll
      for (int c = 0; c < 3; ++c) {
        const long long rr = bm + wm * 128 + r * 16 + (l >> 4) * 4;
        const long long cc = bn + wn * 48 + c * 16 + (l & 15);
        float badd = 0.f;
        if (OMODE == 0) badd = bias[(long long)z * ldc + cc];
#pragma unroll
        for (int i = 0; i < 4; ++i) {
          float v = acc[r][c][i];
          if (OMODE == 0)
            C[czoff + (rr + i) * ldc + cc] = f2bf(v + badd);
          else
            Cf[czoff + (rr + i) * ldc + cc] = v;
        }
      }
    }
  }
}

// f32 -> bf16, 4 elems/thread, grid-stride
__global__ __launch_bounds__(256) void cvt_f32_bf16(
    const float* __restrict__ src, u16* __restrict__ dst, int n4)
{
  int i = blockIdx.x * 256 + threadIdx.x;
  const int stride = gridDim.x * 256;
  for (; i < n4; i += stride) {
    f32x4 v = *(const f32x4*)(src + (long long)i * 4);
    u16x4 o;
    o[0] = f2bf(v[0]); o[1] = f2bf(v[1]);
    o[2] = f2bf(v[2]); o[3] = f2bf(v[3]);
    *(u16x4*)(dst + (long long)i * 4) = o;
  }
}

// W f32 [d][e] -> wt bf16 [z][e][d]
__global__ void prep_w(const float* __restrict__ Wq, const float* __restrict__ Wk,
                       const float* __restrict__ Wv, u16* __restrict__ wt)
{
  __shared__ float tile[32][33];
  const int zz = blockIdx.z;
  const float* W = zz == 0 ? Wq : (zz == 1 ? Wk : Wv);
  const int e0 = blockIdx.x * 32, d0 = blockIdx.y * 32;
  const int tx = threadIdx.x, ty = threadIdx.y;
#pragma unroll
  for (int i = 0; i < 4; ++i)
    tile[ty + i * 8][tx] = W[(long long)(d0 + ty + i * 8) * 768 + e0 + tx];
  __syncthreads();
  u16* dst = wt + (long long)zz * 768 * 768;
#pragma unroll
  for (int i = 0; i < 4; ++i)
    dst[(long long)(e0 + ty + i * 8) * 768 + d0 + tx] = f2bf(tile[tx][ty + i * 8]);
}

// biases f32: pack into contiguous [3][768]
__global__ void prep_b(const float* bq, const float* bk, const float* bv, float* dst)
{
  const int zz = blockIdx.x;
  const float* s = zz == 0 ? bq : (zz == 1 ? bk : bv);
  for (int i = threadIdx.x; i < 768; i += 256) dst[zz * 768 + i] = s[i];
}

// in-place row softmax on bf16 [rows][2048]; one block (256 thr) per row
__global__ __launch_bounds__(256) void softmax_rows(u16* __restrict__ p)
{
  const long long row = blockIdx.x;
  u16* r = p + row * 2048;
  const int t = threadIdx.x;
  const int l = t & 63, w = t >> 6;
  u16x8 vv = *(const u16x8*)(r + t * 8);
  float x[8];
#pragma unroll
  for (int i = 0; i < 8; ++i) x[i] = bf2f(vv[i]);
  float m = x[0];
#pragma unroll
  for (int i = 1; i < 8; ++i) m = fmaxf(m, x[i]);
#pragma unroll
  for (int off = 32; off >= 1; off >>= 1) m = fmaxf(m, __shfl_xor(m, off, 64));
  __shared__ float redm[4], reds[4];
  if (l == 0) redm[w] = m;
  __syncthreads();
  m = fmaxf(fmaxf(redm[0], redm[1]), fmaxf(redm[2], redm[3]));
  float s = 0.f;
#pragma unroll
  for (int i = 0; i < 8; ++i) { x[i] = expf(x[i] - m); s += x[i]; }
#pragma unroll
  for (int off = 32; off >= 1; off >>= 1) s += __shfl_xor(s, off, 64);
  if (l == 0) reds[w] = s;
  __syncthreads();
  s = reds[0] + reds[1] + reds[2] + reds[3];
  const float inv = 1.0f / s;
  u16x8 ov;
#pragma unroll
  for (int i = 0; i < 8; ++i) ov[i] = f2bf(x[i] * inv);
  *(u16x8*)(r + t * 8) = ov;
}

extern "C" void kernel_launch(void* const* d_in, const int* in_sizes, int n_in,
                              void* d_out, int out_size, void* d_ws, size_t ws_size,
                              hipStream_t stream)
{
  (void)in_sizes; (void)n_in; (void)out_size;
  const float* x  = (const float*)d_in[0];
  const float* Wq = (const float*)d_in[1];
  const float* bq = (const float*)d_in[2];
  const float* Wk = (const float*)d_in[3];
  const float* bk = (const float*)d_in[4];
  const float* Wv = (const float*)d_in[5];
  const float* bv = (const float*)d_in[6];
  float* out = (float*)d_out;   // reference output dtype = float32

  // ws layout (bytes): wt @0; qb @3538944; kb follows; vt @79036416;
  // p @104202240 (xb aliased); wsb @171311104. total 171,320,320.
  const size_t NEEDED = 171320320;
  if (ws_size < NEEDED) return;

  char* ws = (char*)d_ws;
  u16* wt  = (u16*)ws;
  u16* qb  = (u16*)(ws + 3538944);
  u16* vt  = (u16*)(ws + 79036416);
  u16* p   = (u16*)(ws + 104202240);
  u16* xb  = p;  // alias: x(bf16) dead before QK^T writes p
  float* wsb = (float*)(ws + 171311104);
  u16* kb = qb + (long long)16384 * 768;

  // allow large dynamic LDS (idempotent; capture-safe)
  (void)hipFuncSetAttribute((const void*)&gemm_bt<1>,
                      hipFuncAttributeMaxDynamicSharedMemorySize, 131072);
  (void)hipFuncSetAttribute((const void*)&gemm_192<0>,
                      hipFuncAttributeMaxDynamicSharedMemorySize, 131072);
  (void)hipFuncSetAttribute((const void*)&gemm_192<2>,
                      hipFuncAttributeMaxDynamicSharedMemorySize, 131072);

  cvt_f32_bf16<<<4096, 256, 0, stream>>>(x, xb, 3145728);
  prep_w<<<dim3(24, 24, 3), dim3(32, 8), 0, stream>>>(Wq, Wk, Wv, wt);
  prep_b<<<3, 256, 0, stream>>>(bq, bk, bv, wsb);

  // q,k,v = x @ W + b — 256x192 tiles, 768 blocks = 3.0 rounds.
  // z==2 (V) writes TRANSPOSED to vt via LDS bounce (coalesced).
  gemm_192<0><<<dim3(64, 4, 3), 512, 114688, stream>>>(
      xb, 0LL, wt, 768LL * 768, qb, nullptr, 16384LL * 768, wsb, vt,
      768, 768, 768, 768);

  // scores = (q @ k^T) / sqrt(768)  per batch — 512 blocks = 2.0 rounds
  gemm_bt<1><<<dim3(8, 8, 8), 512, 131072, stream>>>(
      qb, 2048LL * 768, kb, 2048LL * 768, p, nullptr, 2048LL * 2048, nullptr,
      0.03608439182435161f, 768, 768, 2048, 768);

  softmax_rows<<<16384, 256, 0, stream>>>(p);

  // out = p @ v  per batch -> f32 — 256x192 tiles, 256 blocks = 1.0 round
  gemm_192<2><<<dim3(8, 4, 8), 512, 114688, stream>>>(
      p, 2048LL * 2048, vt, 768LL * 2048, nullptr, out, 2048LL * 768, nullptr,
      nullptr, 2048, 2048, 768, 2048);
}